// Round 9
// baseline (347.079 us; speedup 1.0000x reference)
//
#include <hip/hip_runtime.h>

#define N_NODES 100000
#define N_EDGES 300000
#define N_GRAPHS 4000
#define CAP 32

typedef float f32x4 __attribute__((ext_vector_type(4)));
typedef __bf16 bf16x8 __attribute__((ext_vector_type(8)));
typedef __bf16 bf16x2 __attribute__((ext_vector_type(2)));

// ---------------- workspace layout (float offsets) ----------------
static const size_t OFF_XA    = 0;                                   // N*16: x[9],as1[4],pad[3]
static const size_t OFF_AD4   = OFF_XA + (size_t)N_NODES * 16;       // N*4
static const size_t OFF_AGG   = OFF_AD4 + (size_t)N_NODES * 4;       // N*72 bf16 = N*36 floats
static const size_t OFF_P2B   = OFF_AGG + (size_t)N_NODES * 36;      // N*128 bf16 = N*64 floats
static const size_t OFF_ASAD2 = OFF_P2B + (size_t)N_NODES * 64;      // N*2
static const size_t OFF_WSB   = OFF_ASAD2 + (size_t)N_NODES * 2;     // 65536 bf16 = 32768 floats
static const size_t OFF_INVC  = OFF_WSB + 32768;                     // 4096 floats
static const size_t OFF_INT   = OFF_INVC + 4096;                     // deg[N], bucket[N*CAP]

// k_pre block partition (256 threads each)
#define PRE_NODE_END 391   // ceil(100000/256) node-pack blocks
#define PRE_PACKB_END 455  // +64: 16384 threads x 4 = 65536 W2 elements
#define PRE_DEG_END 846    // +391: zero deg[100000]
#define PRE_OUT_END 1346   // +500: zero out (128000 float4)
#define PRE_INV_END 1362   // +16: inv_cnt[4000]

__device__ __forceinline__ float lrelu(float x) { return x < 0.f ? 0.2f * x : x; }
__device__ __forceinline__ float elu(float x)   { return x > 0.f ? x : __expf(x) - 1.f; }

// Fat pre-kernel: node pack || W2 pack || deg zero || out zero || inv_cnt
__global__ __launch_bounds__(256) void k_pre(
    const float* __restrict__ x, const float* __restrict__ W1,
    const float* __restrict__ a_src1, const float* __restrict__ a_dst1,
    const float* __restrict__ W2, const int* __restrict__ batch,
    float* __restrict__ xa, float* __restrict__ ad4,
    __bf16* __restrict__ wsB, int* __restrict__ deg, float* __restrict__ out,
    float* __restrict__ inv_cnt) {
    int b = blockIdx.x, tid = threadIdx.x;
    if (b < PRE_NODE_END) {
        __shared__ float wf[72];
        if (tid < 72) {
            int isd = tid / 36, r = tid % 36, k = r / 4, h = r % 4;
            const float* a = isd ? a_dst1 : a_src1;
            float s = 0.f;
            for (int c = 0; c < 128; c++) s += W1[k * 512 + h * 128 + c] * a[h * 128 + c];
            wf[tid] = s;
        }
        __syncthreads();
        int n = b * 256 + tid;
        if (n >= N_NODES) return;
        float xv[9];
#pragma unroll
        for (int k = 0; k < 9; k++) xv[k] = x[n * 9 + k];
        float as[4], ad[4];
#pragma unroll
        for (int h = 0; h < 4; h++) {
            float s = 0.f, d = 0.f;
#pragma unroll
            for (int k = 0; k < 9; k++) {
                s += xv[k] * wf[k * 4 + h];
                d += xv[k] * wf[36 + k * 4 + h];
            }
            as[h] = s; ad[h] = d;
        }
        f32x4* xp = (f32x4*)(xa + (size_t)n * 16);
        xp[0] = (f32x4){xv[0], xv[1], xv[2], xv[3]};
        xp[1] = (f32x4){xv[4], xv[5], xv[6], xv[7]};
        xp[2] = (f32x4){xv[8], as[0], as[1], as[2]};
        xp[3] = (f32x4){as[3], 0.f, 0.f, 0.f};
        *(f32x4*)(ad4 + (size_t)n * 4) = (f32x4){ad[0], ad[1], ad[2], ad[3]};
    } else if (b < PRE_PACKB_END) {
        int t = (b - PRE_NODE_END) * 256 + tid;
#pragma unroll
        for (int m = 0; m < 4; m++) {
            int idx = t * 4 + m;                 // 0..65535
            int k = idx >> 7, nn = idx & 127;
            wsB[(size_t)nn * 512 + k] = (__bf16)W2[(size_t)k * 128 + nn];
        }
    } else if (b < PRE_DEG_END) {
        int idx = (b - PRE_PACKB_END) * 256 + tid;
        if (idx < N_NODES) deg[idx] = 0;
    } else if (b < PRE_OUT_END) {
        int idx = (b - PRE_DEG_END) * 256 + tid;  // < 128000 float4s
        if (idx < 128000) ((f32x4*)out)[idx] = (f32x4){0.f, 0.f, 0.f, 0.f};
    } else {
        int g = (b - PRE_OUT_END) * 256 + tid;
        if (g >= N_GRAPHS) return;
        int lo = 0, hi = N_NODES;
        while (lo < hi) { int mid = (lo + hi) >> 1; if (batch[mid] < g) lo = mid + 1; else hi = mid; }
        int s = lo; hi = N_NODES;
        while (lo < hi) { int mid = (lo + hi) >> 1; if (batch[mid] < g + 1) lo = mid + 1; else hi = mid; }
        int c = lo - s;
        inv_cnt[g] = 1.f / (float)(c > 0 ? c : 1);
    }
}

// build per-dst bucket of src ids
__global__ void k_bucket(const int* __restrict__ ei, int* __restrict__ deg,
                         int* __restrict__ bucket) {
    int e = blockIdx.x * 256 + threadIdx.x;
    if (e >= N_EDGES) return;
    int s = ei[e], d = ei[N_EDGES + e];
    int slot = atomicAdd(&deg[d], 1);
    if (slot < CAP) bucket[d * CAP + slot] = s;
}

// Layer-1 attention aggregation (standalone, latency-optimized: high occupancy).
// 8 threads/node, shuffle-reduce; writes agg[n][72] bf16 (head h at h*16, 9 valid).
__global__ void k_agg(const float* __restrict__ xa, const float* __restrict__ ad4,
                      const int* __restrict__ deg, const int* __restrict__ bucket,
                      __bf16* __restrict__ agg) {
    int t = blockIdx.x * 256 + threadIdx.x;
    int n = t >> 3, s = t & 7;
    if (n >= N_NODES) return;
    float acc[4][9] = {};
    float z[4] = {0.f, 0.f, 0.f, 0.f};
    f32x4 adv = *(const f32x4*)(ad4 + (size_t)n * 4);
    float ad[4] = {adv.x, adv.y, adv.z, adv.w};
    int dg = deg[n];
    if (dg > CAP) dg = CAP;
    if (s == 0) {
        const f32x4* xp = (const f32x4*)(xa + (size_t)n * 16);
        f32x4 v0 = xp[0], v1 = xp[1], v2 = xp[2], v3 = xp[3];
        float xs[9] = {v0.x, v0.y, v0.z, v0.w, v1.x, v1.y, v1.z, v1.w, v2.x};
        float asl[4] = {v2.y, v2.z, v2.w, v3.x};
#pragma unroll
        for (int h = 0; h < 4; h++) {
            float e = __expf(lrelu(asl[h] + ad[h]));
            z[h] += e;
#pragma unroll
            for (int k = 0; k < 9; k++) acc[h][k] += e * xs[k];
        }
    } else {
        for (int j = s - 1; j < dg; j += 7) {
            int src = bucket[n * CAP + j];
            const f32x4* xp = (const f32x4*)(xa + (size_t)src * 16);
            f32x4 v0 = xp[0], v1 = xp[1], v2 = xp[2], v3 = xp[3];
            float xs[9] = {v0.x, v0.y, v0.z, v0.w, v1.x, v1.y, v1.z, v1.w, v2.x};
            float asl[4] = {v2.y, v2.z, v2.w, v3.x};
#pragma unroll
            for (int h = 0; h < 4; h++) {
                float e = __expf(lrelu(asl[h] + ad[h]));
                z[h] += e;
#pragma unroll
                for (int k = 0; k < 9; k++) acc[h][k] += e * xs[k];
            }
        }
    }
#pragma unroll
    for (int off = 1; off < 8; off <<= 1) {
#pragma unroll
        for (int h = 0; h < 4; h++) {
            z[h] += __shfl_xor(z[h], off);
#pragma unroll
            for (int k = 0; k < 9; k++) acc[h][k] += __shfl_xor(acc[h][k], off);
        }
    }
    if (s < 4) {   // thread s writes head s: 16 bf16 (9 valid, rest zero)
        float inv = 1.f / z[s];
        bf16x8 p0, p1;
#pragma unroll
        for (int k = 0; k < 8; k++) p0[k] = (__bf16)(acc[s][k] * inv);
        p1[0] = (__bf16)(acc[s][8] * inv);
#pragma unroll
        for (int k = 1; k < 8; k++) p1[k] = (__bf16)0.f;
        __bf16* dst = agg + (size_t)n * 72 + s * 16;
        *(bf16x8*)dst = p0;
        *(bf16x8*)(dst + 8) = p1;
    }
}

// GEMM: stage agg tile -> LDS; phase1 h2=elu(agg@W1+b1) -> bf16 frag-major As;
// phase2 MFMA with B fully register-resident; epilogue p2b + asad2.
__global__ __launch_bounds__(512, 4) void k_gemm(
    const __bf16* __restrict__ agg, const float* __restrict__ W1,
    const float* __restrict__ b1, const __bf16* __restrict__ wsB,
    const float* __restrict__ a_src2, const float* __restrict__ a_dst2,
    __bf16* __restrict__ p2b, float* __restrict__ asad2) {
    __shared__ __bf16 As[64 * 512];    // 64 KB frag-major: tile t=rt*16+kc, chunk lane*8
    __shared__ __bf16 AgT[64 * 72];    // 9.2 KB
    __shared__ float red2[64 * 16];    // 4 KB
    const int tid = threadIdx.x;
    const int lane = tid & 63;
    const int w = tid >> 6;
    const int i = lane & 15;
    const int q = lane >> 4;
    const int m0 = blockIdx.x * 64;

    // ---- B preload: wave w owns cols [w*16, w*16+16), full K in 64 VGPRs ----
    bf16x8 breg[16];
    {
        const __bf16* bp = wsB + (size_t)(w * 16 + i) * 512 + q * 8;
#pragma unroll
        for (int kc = 0; kc < 16; kc++) breg[kc] = *(const bf16x8*)(bp + kc * 32);
    }

    // ---- stage agg tile (64 x 72 bf16 = 576 bf16x8 chunks) ----
    for (int idx = tid; idx < 576; idx += 512) {
        int row = idx / 9, c8 = idx - row * 9;
        int gr = m0 + row;
        bf16x8 v;
        if (gr < N_NODES) v = *(const bf16x8*)(agg + (size_t)gr * 72 + c8 * 8);
        else {
#pragma unroll
            for (int k = 0; k < 8; k++) v[k] = (__bf16)0.f;
        }
        *(bf16x8*)&AgT[row * 72 + c8 * 8] = v;
    }
    __syncthreads();

    // ---- phase 1: thread = (row=tid&63, kg=tid>>6); 64 cols each ----
    {
        int row = tid & 63;
        int kg = __builtin_amdgcn_readfirstlane(tid >> 6);  // wave-uniform -> scalar W1 loads
        int h = kg >> 1;
        float ag[9];
        {
            bf16x8 a8 = *(const bf16x8*)&AgT[row * 72 + h * 16];
#pragma unroll
            for (int k = 0; k < 8; k++) ag[k] = (float)a8[k];
            ag[8] = (float)AgT[row * 72 + h * 16 + 8];
        }
        int rt = row >> 4, il = row & 15;
#pragma unroll
        for (int c8 = 0; c8 < 8; c8++) {
            int j0 = kg * 64 + c8 * 8;
            float o[8];
#pragma unroll
            for (int e = 0; e < 8; e++) o[e] = b1[j0 + e];
#pragma unroll
            for (int k = 0; k < 9; k++) {
                const float* wp = &W1[k * 512 + j0];
#pragma unroll
                for (int e = 0; e < 8; e++) o[e] += ag[k] * wp[e];
            }
            bf16x8 pk;
#pragma unroll
            for (int e = 0; e < 8; e++) pk[e] = (__bf16)elu(o[e]);
            int tile = rt * 16 + (kg * 2 + (c8 >> 2));
            *(bf16x8*)&As[tile * 512 + ((c8 & 3) * 16 + il) * 8] = pk;
        }
    }
    __syncthreads();

    // ---- phase 2: MFMA sweep, B in regs, no barriers ----
    f32x4 acc[4];
#pragma unroll
    for (int r = 0; r < 4; r++) acc[r] = (f32x4){0.f, 0.f, 0.f, 0.f};
#pragma unroll
    for (int kc = 0; kc < 16; kc++) {
#pragma unroll
        for (int rt = 0; rt < 4; rt++) {
            bf16x8 af = *(const bf16x8*)&As[(rt * 16 + kc) * 512 + lane * 8];
            acc[rt] = __builtin_amdgcn_mfma_f32_16x16x32_bf16(af, breg[kc], acc[rt], 0, 0, 0);
        }
    }

    // ---- epilogue: p2 (bf16) + asad2 via LDS cross-wave reduction ----
    float as2 = a_src2[w * 16 + i];
    float ad2 = a_dst2[w * 16 + i];
#pragma unroll
    for (int rt = 0; rt < 4; rt++) {
#pragma unroll
        for (int qq = 0; qq < 4; qq++) {
            int row = rt * 16 + q * 4 + qq;
            float v = acc[rt][qq];
            if (m0 + row < N_NODES)
                p2b[(size_t)(m0 + row) * 128 + w * 16 + i] = (__bf16)v;
            float s = v * as2, d = v * ad2;
#pragma unroll
            for (int off = 1; off < 16; off <<= 1) {
                s += __shfl_xor(s, off);
                d += __shfl_xor(d, off);
            }
            if (i == 0) {
                red2[row * 16 + w * 2] = s;
                red2[row * 16 + w * 2 + 1] = d;
            }
        }
    }
    __syncthreads();
    if (tid < 128) {
        int row = tid >> 1, cc = tid & 1;
        float sum = 0.f;
#pragma unroll
        for (int ww = 0; ww < 8; ww++) sum += red2[row * 16 + ww * 2 + cc];
        if (m0 + row < N_NODES) asad2[(size_t)(m0 + row) * 2 + cc] = sum;
    }
}

// layer-2 attention + aggregation + elu + fused graph-MEAN (inv_cnt folded in).
__global__ void k_agg2_pool(const __bf16* __restrict__ p2b, const float* __restrict__ asad2,
                            const int* __restrict__ deg, const int* __restrict__ bucket,
                            const float* __restrict__ b2, const int* __restrict__ batch,
                            const float* __restrict__ inv_cnt, float* __restrict__ out) {
    int wv = (blockIdx.x * 256 + threadIdx.x) >> 6;
    wv = __builtin_amdgcn_readfirstlane(wv);
    int lane = threadIdx.x & 63;
    int nbase = wv * 8;
    if (nbase >= N_NODES) return;
    int nend = nbase + 8;
    if (nend > N_NODES) nend = N_NODES;
    float b2a = b2[2 * lane], b2b = b2[2 * lane + 1];
    float g0 = 0.f, g1 = 0.f;
    int curg = batch[nbase];
    for (int n = nbase; n < nend; n++) {
        float ad = asad2[n * 2 + 1];
        float e = __expf(lrelu(asad2[n * 2] + ad));  // self loop
        float z = e;
        bf16x2 v = ((const bf16x2*)(p2b + (size_t)n * 128))[lane];
        float a0 = e * (float)v.x;
        float a1 = e * (float)v.y;
        int dg = deg[n];
        if (dg > CAP) dg = CAP;
        for (int j = 0; j < dg; j++) {
            int s = bucket[n * CAP + j];
            float e2 = __expf(lrelu(asad2[s * 2] + ad));
            z += e2;
            bf16x2 sv = ((const bf16x2*)(p2b + (size_t)s * 128))[lane];
            a0 += e2 * (float)sv.x;
            a1 += e2 * (float)sv.y;
        }
        float inv = 1.f / z;
        float o0 = elu(a0 * inv + b2a);
        float o1 = elu(a1 * inv + b2b);
        int g = batch[n];
        if (g != curg) {
            float ic = inv_cnt[curg];
            atomicAdd(&out[(size_t)curg * 128 + 2 * lane], g0 * ic);
            atomicAdd(&out[(size_t)curg * 128 + 2 * lane + 1], g1 * ic);
            g0 = 0.f; g1 = 0.f; curg = g;
        }
        g0 += o0; g1 += o1;
    }
    float ic = inv_cnt[curg];
    atomicAdd(&out[(size_t)curg * 128 + 2 * lane], g0 * ic);
    atomicAdd(&out[(size_t)curg * 128 + 2 * lane + 1], g1 * ic);
}

extern "C" void kernel_launch(void* const* d_in, const int* in_sizes, int n_in,
                              void* d_out, int out_size, void* d_ws, size_t ws_size,
                              hipStream_t stream) {
    const float* x       = (const float*)d_in[0];
    const int*   ei      = (const int*)d_in[1];
    const int*   batch   = (const int*)d_in[2];
    const float* W1      = (const float*)d_in[3];
    const float* a_src1  = (const float*)d_in[4];
    const float* a_dst1  = (const float*)d_in[5];
    const float* b1      = (const float*)d_in[6];
    const float* W2      = (const float*)d_in[7];
    const float* a_src2  = (const float*)d_in[8];
    const float* a_dst2  = (const float*)d_in[9];
    const float* b2      = (const float*)d_in[10];
    float* out = (float*)d_out;

    float* wsf   = (float*)d_ws;
    float* xa    = wsf + OFF_XA;
    float* ad4   = wsf + OFF_AD4;
    __bf16* agg  = (__bf16*)(wsf + OFF_AGG);
    __bf16* p2b  = (__bf16*)(wsf + OFF_P2B);
    float* asad2 = wsf + OFF_ASAD2;
    __bf16* wsB  = (__bf16*)(wsf + OFF_WSB);
    float* invc  = wsf + OFF_INVC;
    int* wsi    = (int*)(wsf + OFF_INT);
    int* deg    = wsi;
    int* bucket = wsi + N_NODES;

    k_pre<<<PRE_INV_END, 256, 0, stream>>>(x, W1, a_src1, a_dst1, W2, batch,
                                           xa, ad4, wsB, deg, out, invc);
    k_bucket<<<(N_EDGES + 255) / 256, 256, 0, stream>>>(ei, deg, bucket);
    k_agg<<<(N_NODES * 8 + 255) / 256, 256, 0, stream>>>(xa, ad4, deg, bucket, agg);
    k_gemm<<<(N_NODES + 63) / 64, 512, 0, stream>>>(agg, W1, b1, wsB,
                                                    a_src2, a_dst2, p2b, asad2);
    k_agg2_pool<<<((N_NODES + 7) / 8 * 64 + 255) / 256, 256, 0, stream>>>(
        p2b, asad2, deg, bucket, b2, batch, invc, out);
}

// Round 10
// 224.583 us; speedup vs baseline: 1.5454x; 1.5454x over previous
//
#include <hip/hip_runtime.h>

#define N_NODES 100000
#define N_EDGES 300000
#define N_GRAPHS 4000
#define CAP 32

typedef float f32x4 __attribute__((ext_vector_type(4)));
typedef __bf16 bf16x8 __attribute__((ext_vector_type(8)));
typedef __bf16 bf16x2 __attribute__((ext_vector_type(2)));

// ---------------- workspace layout (float offsets) ----------------
static const size_t OFF_XA    = 0;                                   // N*16: x[9],as1[4],pad[3]
static const size_t OFF_AD4   = OFF_XA + (size_t)N_NODES * 16;       // N*4
static const size_t OFF_AGG   = OFF_AD4 + (size_t)N_NODES * 4;       // N*72 bf16 = N*36 floats
static const size_t OFF_P2B   = OFF_AGG + (size_t)N_NODES * 36;      // N*128 bf16 = N*64 floats
static const size_t OFF_ASAD2 = OFF_P2B + (size_t)N_NODES * 64;      // N*2
static const size_t OFF_WSB   = OFF_ASAD2 + (size_t)N_NODES * 2;     // 65536 bf16 = 32768 floats
static const size_t OFF_INVC  = OFF_WSB + 32768;                     // 4096 floats
static const size_t OFF_INT   = OFF_INVC + 4096;                     // deg[N], bucket[N*CAP]

// k_pre block partition (256 threads each)
#define PRE_NODE_END 391   // ceil(100000/256) node-pack blocks
#define PRE_PACKB_END 455  // +64: 16384 threads x 4 = 65536 W2 elements
#define PRE_DEG_END 846    // +391: zero deg[100000]
#define PRE_OUT_END 1346   // +500: zero out (128000 float4)
#define PRE_INV_END 1362   // +16: inv_cnt[4000]

__device__ __forceinline__ float lrelu(float x) { return x < 0.f ? 0.2f * x : x; }
__device__ __forceinline__ float elu(float x)   { return x > 0.f ? x : __expf(x) - 1.f; }

// Fat pre-kernel: node pack || W2 pack || deg zero || out zero || inv_cnt
__global__ __launch_bounds__(256) void k_pre(
    const float* __restrict__ x, const float* __restrict__ W1,
    const float* __restrict__ a_src1, const float* __restrict__ a_dst1,
    const float* __restrict__ W2, const int* __restrict__ batch,
    float* __restrict__ xa, float* __restrict__ ad4,
    __bf16* __restrict__ wsB, int* __restrict__ deg, float* __restrict__ out,
    float* __restrict__ inv_cnt) {
    int b = blockIdx.x, tid = threadIdx.x;
    if (b < PRE_NODE_END) {
        __shared__ float wf[72];
        if (tid < 72) {
            int isd = tid / 36, r = tid % 36, k = r / 4, h = r % 4;
            const float* a = isd ? a_dst1 : a_src1;
            float s = 0.f;
            for (int c = 0; c < 128; c++) s += W1[k * 512 + h * 128 + c] * a[h * 128 + c];
            wf[tid] = s;
        }
        __syncthreads();
        int n = b * 256 + tid;
        if (n >= N_NODES) return;
        float xv[9];
#pragma unroll
        for (int k = 0; k < 9; k++) xv[k] = x[n * 9 + k];
        float as[4], ad[4];
#pragma unroll
        for (int h = 0; h < 4; h++) {
            float s = 0.f, d = 0.f;
#pragma unroll
            for (int k = 0; k < 9; k++) {
                s += xv[k] * wf[k * 4 + h];
                d += xv[k] * wf[36 + k * 4 + h];
            }
            as[h] = s; ad[h] = d;
        }
        f32x4* xp = (f32x4*)(xa + (size_t)n * 16);
        xp[0] = (f32x4){xv[0], xv[1], xv[2], xv[3]};
        xp[1] = (f32x4){xv[4], xv[5], xv[6], xv[7]};
        xp[2] = (f32x4){xv[8], as[0], as[1], as[2]};
        xp[3] = (f32x4){as[3], 0.f, 0.f, 0.f};
        *(f32x4*)(ad4 + (size_t)n * 4) = (f32x4){ad[0], ad[1], ad[2], ad[3]};
    } else if (b < PRE_PACKB_END) {
        int t = (b - PRE_NODE_END) * 256 + tid;
#pragma unroll
        for (int m = 0; m < 4; m++) {
            int idx = t * 4 + m;                 // 0..65535
            int k = idx >> 7, nn = idx & 127;
            wsB[(size_t)nn * 512 + k] = (__bf16)W2[(size_t)k * 128 + nn];
        }
    } else if (b < PRE_DEG_END) {
        int idx = (b - PRE_PACKB_END) * 256 + tid;
        if (idx < N_NODES) deg[idx] = 0;
    } else if (b < PRE_OUT_END) {
        int idx = (b - PRE_DEG_END) * 256 + tid;  // < 128000 float4s
        if (idx < 128000) ((f32x4*)out)[idx] = (f32x4){0.f, 0.f, 0.f, 0.f};
    } else {
        int g = (b - PRE_OUT_END) * 256 + tid;
        if (g >= N_GRAPHS) return;
        int lo = 0, hi = N_NODES;
        while (lo < hi) { int mid = (lo + hi) >> 1; if (batch[mid] < g) lo = mid + 1; else hi = mid; }
        int s = lo; hi = N_NODES;
        while (lo < hi) { int mid = (lo + hi) >> 1; if (batch[mid] < g + 1) lo = mid + 1; else hi = mid; }
        int c = lo - s;
        inv_cnt[g] = 1.f / (float)(c > 0 ? c : 1);
    }
}

// build per-dst bucket of src ids
__global__ void k_bucket(const int* __restrict__ ei, int* __restrict__ deg,
                         int* __restrict__ bucket) {
    int e = blockIdx.x * 256 + threadIdx.x;
    if (e >= N_EDGES) return;
    int s = ei[e], d = ei[N_EDGES + e];
    int slot = atomicAdd(&deg[d], 1);
    if (slot < CAP) bucket[d * CAP + slot] = s;
}

// Layer-1 attention aggregation: ONE THREAD PER (node, head).
// Live state ~12 floats -> no spill. 4 lanes of a node share neighbor
// addresses (broadcast); xa is 6.4 MB -> L2-resident.
__global__ void k_agg(const float* __restrict__ xa, const float* __restrict__ ad4,
                      const int* __restrict__ deg, const int* __restrict__ bucket,
                      __bf16* __restrict__ agg) {
    int t = blockIdx.x * 256 + threadIdx.x;
    int n = t >> 2, h = t & 3;
    if (n >= N_NODES) return;
    float ad = ad4[(size_t)n * 4 + h];
    int dg = deg[n];
    if (dg > CAP) dg = CAP;
    float acc[9] = {};
    float z = 0.f;
    // self loop
    {
        const f32x4* xp = (const f32x4*)(xa + (size_t)n * 16);
        f32x4 v0 = xp[0], v1 = xp[1], v2 = xp[2], v3 = xp[3];
        float asl = (h == 0) ? v2.y : (h == 1) ? v2.z : (h == 2) ? v2.w : v3.x;
        float e = __expf(lrelu(asl + ad));
        z += e;
        acc[0] += e * v0.x; acc[1] += e * v0.y; acc[2] += e * v0.z; acc[3] += e * v0.w;
        acc[4] += e * v1.x; acc[5] += e * v1.y; acc[6] += e * v1.z; acc[7] += e * v1.w;
        acc[8] += e * v2.x;
    }
    for (int j = 0; j < dg; j++) {
        int src = bucket[n * CAP + j];
        const f32x4* xp = (const f32x4*)(xa + (size_t)src * 16);
        f32x4 v0 = xp[0], v1 = xp[1], v2 = xp[2], v3 = xp[3];
        float asl = (h == 0) ? v2.y : (h == 1) ? v2.z : (h == 2) ? v2.w : v3.x;
        float e = __expf(lrelu(asl + ad));
        z += e;
        acc[0] += e * v0.x; acc[1] += e * v0.y; acc[2] += e * v0.z; acc[3] += e * v0.w;
        acc[4] += e * v1.x; acc[5] += e * v1.y; acc[6] += e * v1.z; acc[7] += e * v1.w;
        acc[8] += e * v2.x;
    }
    float inv = 1.f / z;
    bf16x8 p0;
#pragma unroll
    for (int k = 0; k < 8; k++) p0[k] = (__bf16)(acc[k] * inv);
    __bf16* dst = agg + (size_t)n * 72 + h * 16;
    *(bf16x8*)dst = p0;
    dst[8] = (__bf16)(acc[8] * inv);
}

// GEMM: stage agg tile -> LDS; phase1 h2=elu(agg@W1+b1) -> bf16 frag-major As;
// phase2 MFMA with B fully register-resident; epilogue p2b + asad2.
__global__ __launch_bounds__(512, 4) void k_gemm(
    const __bf16* __restrict__ agg, const float* __restrict__ W1,
    const float* __restrict__ b1, const __bf16* __restrict__ wsB,
    const float* __restrict__ a_src2, const float* __restrict__ a_dst2,
    __bf16* __restrict__ p2b, float* __restrict__ asad2) {
    __shared__ __bf16 As[64 * 512];    // 64 KB frag-major: tile t=rt*16+kc, chunk lane*8
    __shared__ __bf16 AgT[64 * 72];    // 9.2 KB
    __shared__ float red2[64 * 16];    // 4 KB
    const int tid = threadIdx.x;
    const int lane = tid & 63;
    const int w = tid >> 6;
    const int i = lane & 15;
    const int q = lane >> 4;
    const int m0 = blockIdx.x * 64;

    // ---- B preload: wave w owns cols [w*16, w*16+16), full K in 64 VGPRs ----
    bf16x8 breg[16];
    {
        const __bf16* bp = wsB + (size_t)(w * 16 + i) * 512 + q * 8;
#pragma unroll
        for (int kc = 0; kc < 16; kc++) breg[kc] = *(const bf16x8*)(bp + kc * 32);
    }

    // ---- stage agg tile (64 x 72 bf16 = 576 bf16x8 chunks) ----
    for (int idx = tid; idx < 576; idx += 512) {
        int row = idx / 9, c8 = idx - row * 9;
        int gr = m0 + row;
        bf16x8 v;
        if (gr < N_NODES) v = *(const bf16x8*)(agg + (size_t)gr * 72 + c8 * 8);
        else {
#pragma unroll
            for (int k = 0; k < 8; k++) v[k] = (__bf16)0.f;
        }
        *(bf16x8*)&AgT[row * 72 + c8 * 8] = v;
    }
    __syncthreads();

    // ---- phase 1: thread = (row=tid&63, kg=tid>>6); 64 cols each ----
    {
        int row = tid & 63;
        int kg = __builtin_amdgcn_readfirstlane(tid >> 6);  // wave-uniform -> scalar W1 loads
        int h = kg >> 1;
        float ag[9];
        {
            bf16x8 a8 = *(const bf16x8*)&AgT[row * 72 + h * 16];
#pragma unroll
            for (int k = 0; k < 8; k++) ag[k] = (float)a8[k];
            ag[8] = (float)AgT[row * 72 + h * 16 + 8];
        }
        int rt = row >> 4, il = row & 15;
#pragma unroll
        for (int c8 = 0; c8 < 8; c8++) {
            int j0 = kg * 64 + c8 * 8;
            float o[8];
#pragma unroll
            for (int e = 0; e < 8; e++) o[e] = b1[j0 + e];
#pragma unroll
            for (int k = 0; k < 9; k++) {
                const float* wp = &W1[k * 512 + j0];
#pragma unroll
                for (int e = 0; e < 8; e++) o[e] += ag[k] * wp[e];
            }
            bf16x8 pk;
#pragma unroll
            for (int e = 0; e < 8; e++) pk[e] = (__bf16)elu(o[e]);
            int tile = rt * 16 + (kg * 2 + (c8 >> 2));
            *(bf16x8*)&As[tile * 512 + ((c8 & 3) * 16 + il) * 8] = pk;
        }
    }
    __syncthreads();

    // ---- phase 2: MFMA sweep, B in regs, no barriers ----
    f32x4 acc[4];
#pragma unroll
    for (int r = 0; r < 4; r++) acc[r] = (f32x4){0.f, 0.f, 0.f, 0.f};
#pragma unroll
    for (int kc = 0; kc < 16; kc++) {
#pragma unroll
        for (int rt = 0; rt < 4; rt++) {
            bf16x8 af = *(const bf16x8*)&As[(rt * 16 + kc) * 512 + lane * 8];
            acc[rt] = __builtin_amdgcn_mfma_f32_16x16x32_bf16(af, breg[kc], acc[rt], 0, 0, 0);
        }
    }

    // ---- epilogue: p2 (bf16) + asad2 via LDS cross-wave reduction ----
    float as2 = a_src2[w * 16 + i];
    float ad2 = a_dst2[w * 16 + i];
#pragma unroll
    for (int rt = 0; rt < 4; rt++) {
#pragma unroll
        for (int qq = 0; qq < 4; qq++) {
            int row = rt * 16 + q * 4 + qq;
            float v = acc[rt][qq];
            if (m0 + row < N_NODES)
                p2b[(size_t)(m0 + row) * 128 + w * 16 + i] = (__bf16)v;
            float s = v * as2, d = v * ad2;
#pragma unroll
            for (int off = 1; off < 16; off <<= 1) {
                s += __shfl_xor(s, off);
                d += __shfl_xor(d, off);
            }
            if (i == 0) {
                red2[row * 16 + w * 2] = s;
                red2[row * 16 + w * 2 + 1] = d;
            }
        }
    }
    __syncthreads();
    if (tid < 128) {
        int row = tid >> 1, cc = tid & 1;
        float sum = 0.f;
#pragma unroll
        for (int ww = 0; ww < 8; ww++) sum += red2[row * 16 + ww * 2 + cc];
        if (m0 + row < N_NODES) asad2[(size_t)(m0 + row) * 2 + cc] = sum;
    }
}

// layer-2 attention + aggregation + elu + fused graph-MEAN (inv_cnt folded in).
__global__ void k_agg2_pool(const __bf16* __restrict__ p2b, const float* __restrict__ asad2,
                            const int* __restrict__ deg, const int* __restrict__ bucket,
                            const float* __restrict__ b2, const int* __restrict__ batch,
                            const float* __restrict__ inv_cnt, float* __restrict__ out) {
    int wv = (blockIdx.x * 256 + threadIdx.x) >> 6;
    wv = __builtin_amdgcn_readfirstlane(wv);
    int lane = threadIdx.x & 63;
    int nbase = wv * 8;
    if (nbase >= N_NODES) return;
    int nend = nbase + 8;
    if (nend > N_NODES) nend = N_NODES;
    float b2a = b2[2 * lane], b2b = b2[2 * lane + 1];
    float g0 = 0.f, g1 = 0.f;
    int curg = batch[nbase];
    for (int n = nbase; n < nend; n++) {
        float ad = asad2[n * 2 + 1];
        float e = __expf(lrelu(asad2[n * 2] + ad));  // self loop
        float z = e;
        bf16x2 v = ((const bf16x2*)(p2b + (size_t)n * 128))[lane];
        float a0 = e * (float)v.x;
        float a1 = e * (float)v.y;
        int dg = deg[n];
        if (dg > CAP) dg = CAP;
        for (int j = 0; j < dg; j++) {
            int s = bucket[n * CAP + j];
            float e2 = __expf(lrelu(asad2[s * 2] + ad));
            z += e2;
            bf16x2 sv = ((const bf16x2*)(p2b + (size_t)s * 128))[lane];
            a0 += e2 * (float)sv.x;
            a1 += e2 * (float)sv.y;
        }
        float inv = 1.f / z;
        float o0 = elu(a0 * inv + b2a);
        float o1 = elu(a1 * inv + b2b);
        int g = batch[n];
        if (g != curg) {
            float ic = inv_cnt[curg];
            atomicAdd(&out[(size_t)curg * 128 + 2 * lane], g0 * ic);
            atomicAdd(&out[(size_t)curg * 128 + 2 * lane + 1], g1 * ic);
            g0 = 0.f; g1 = 0.f; curg = g;
        }
        g0 += o0; g1 += o1;
    }
    float ic = inv_cnt[curg];
    atomicAdd(&out[(size_t)curg * 128 + 2 * lane], g0 * ic);
    atomicAdd(&out[(size_t)curg * 128 + 2 * lane + 1], g1 * ic);
}

extern "C" void kernel_launch(void* const* d_in, const int* in_sizes, int n_in,
                              void* d_out, int out_size, void* d_ws, size_t ws_size,
                              hipStream_t stream) {
    const float* x       = (const float*)d_in[0];
    const int*   ei      = (const int*)d_in[1];
    const int*   batch   = (const int*)d_in[2];
    const float* W1      = (const float*)d_in[3];
    const float* a_src1  = (const float*)d_in[4];
    const float* a_dst1  = (const float*)d_in[5];
    const float* b1      = (const float*)d_in[6];
    const float* W2      = (const float*)d_in[7];
    const float* a_src2  = (const float*)d_in[8];
    const float* a_dst2  = (const float*)d_in[9];
    const float* b2      = (const float*)d_in[10];
    float* out = (float*)d_out;

    float* wsf   = (float*)d_ws;
    float* xa    = wsf + OFF_XA;
    float* ad4   = wsf + OFF_AD4;
    __bf16* agg  = (__bf16*)(wsf + OFF_AGG);
    __bf16* p2b  = (__bf16*)(wsf + OFF_P2B);
    float* asad2 = wsf + OFF_ASAD2;
    __bf16* wsB  = (__bf16*)(wsf + OFF_WSB);
    float* invc  = wsf + OFF_INVC;
    int* wsi    = (int*)(wsf + OFF_INT);
    int* deg    = wsi;
    int* bucket = wsi + N_NODES;

    k_pre<<<PRE_INV_END, 256, 0, stream>>>(x, W1, a_src1, a_dst1, W2, batch,
                                           xa, ad4, wsB, deg, out, invc);
    k_bucket<<<(N_EDGES + 255) / 256, 256, 0, stream>>>(ei, deg, bucket);
    k_agg<<<(N_NODES * 4 + 255) / 256, 256, 0, stream>>>(xa, ad4, deg, bucket, agg);
    k_gemm<<<(N_NODES + 63) / 64, 512, 0, stream>>>(agg, W1, b1, wsB,
                                                    a_src2, a_dst2, p2b, asad2);
    k_agg2_pool<<<((N_NODES + 7) / 8 * 64 + 255) / 256, 256, 0, stream>>>(
        p2b, asad2, deg, bucket, b2, batch, invc, out);
}

// Round 11
// 217.012 us; speedup vs baseline: 1.5994x; 1.0349x over previous
//
#include <hip/hip_runtime.h>

#define N_NODES 100000
#define N_EDGES 300000
#define N_GRAPHS 4000
#define CAP 32

typedef float f32x4 __attribute__((ext_vector_type(4)));
typedef __bf16 bf16x8 __attribute__((ext_vector_type(8)));
typedef __bf16 bf16x2 __attribute__((ext_vector_type(2)));

// ---------------- workspace layout (float offsets) ----------------
static const size_t OFF_XA    = 0;                                   // N*16: x[9],as1[4],pad[3]
static const size_t OFF_AD4   = OFF_XA + (size_t)N_NODES * 16;       // N*4
static const size_t OFF_P2B   = OFF_AD4 + (size_t)N_NODES * 4;       // N*128 bf16 = N*64 floats
static const size_t OFF_ASAD2 = OFF_P2B + (size_t)N_NODES * 64;      // N*2
static const size_t OFF_WSB   = OFF_ASAD2 + (size_t)N_NODES * 2;     // 65536 bf16 = 32768 floats
static const size_t OFF_INVC  = OFF_WSB + 32768;                     // 4096 floats
static const size_t OFF_INT   = OFF_INVC + 4096;                     // deg[N], bucket[N*CAP]

// k_pre block partition (256 threads each)
#define PRE_NODE_END 391   // ceil(100000/256) node-pack blocks
#define PRE_PACKB_END 455  // +64: 16384 threads x 4 = 65536 W2 elements
#define PRE_DEG_END 846    // +391: zero deg[100000]
#define PRE_OUT_END 1346   // +500: zero out (128000 float4)
#define PRE_INV_END 1362   // +16: inv_cnt[4000]

__device__ __forceinline__ float lrelu(float x) { return x < 0.f ? 0.2f * x : x; }
__device__ __forceinline__ float elu(float x)   { return x > 0.f ? x : __expf(x) - 1.f; }

// Fat pre-kernel: node pack || W2 pack || deg zero || out zero || inv_cnt
__global__ __launch_bounds__(256) void k_pre(
    const float* __restrict__ x, const float* __restrict__ W1,
    const float* __restrict__ a_src1, const float* __restrict__ a_dst1,
    const float* __restrict__ W2, const int* __restrict__ batch,
    float* __restrict__ xa, float* __restrict__ ad4,
    __bf16* __restrict__ wsB, int* __restrict__ deg, float* __restrict__ out,
    float* __restrict__ inv_cnt) {
    int b = blockIdx.x, tid = threadIdx.x;
    if (b < PRE_NODE_END) {
        __shared__ float wf[72];
        if (tid < 72) {
            int isd = tid / 36, r = tid % 36, k = r / 4, h = r % 4;
            const float* a = isd ? a_dst1 : a_src1;
            float s = 0.f;
            for (int c = 0; c < 128; c++) s += W1[k * 512 + h * 128 + c] * a[h * 128 + c];
            wf[tid] = s;
        }
        __syncthreads();
        int n = b * 256 + tid;
        if (n >= N_NODES) return;
        float xv[9];
#pragma unroll
        for (int k = 0; k < 9; k++) xv[k] = x[n * 9 + k];
        float as[4], ad[4];
#pragma unroll
        for (int h = 0; h < 4; h++) {
            float s = 0.f, d = 0.f;
#pragma unroll
            for (int k = 0; k < 9; k++) {
                s += xv[k] * wf[k * 4 + h];
                d += xv[k] * wf[36 + k * 4 + h];
            }
            as[h] = s; ad[h] = d;
        }
        f32x4* xp = (f32x4*)(xa + (size_t)n * 16);
        xp[0] = (f32x4){xv[0], xv[1], xv[2], xv[3]};
        xp[1] = (f32x4){xv[4], xv[5], xv[6], xv[7]};
        xp[2] = (f32x4){xv[8], as[0], as[1], as[2]};
        xp[3] = (f32x4){as[3], 0.f, 0.f, 0.f};
        *(f32x4*)(ad4 + (size_t)n * 4) = (f32x4){ad[0], ad[1], ad[2], ad[3]};
    } else if (b < PRE_PACKB_END) {
        int t = (b - PRE_NODE_END) * 256 + tid;
#pragma unroll
        for (int m = 0; m < 4; m++) {
            int idx = t * 4 + m;                 // 0..65535
            int k = idx >> 7, nn = idx & 127;
            wsB[(size_t)nn * 512 + k] = (__bf16)W2[(size_t)k * 128 + nn];
        }
    } else if (b < PRE_DEG_END) {
        int idx = (b - PRE_PACKB_END) * 256 + tid;
        if (idx < N_NODES) deg[idx] = 0;
    } else if (b < PRE_OUT_END) {
        int idx = (b - PRE_DEG_END) * 256 + tid;  // < 128000 float4s
        if (idx < 128000) ((f32x4*)out)[idx] = (f32x4){0.f, 0.f, 0.f, 0.f};
    } else {
        int g = (b - PRE_OUT_END) * 256 + tid;
        if (g >= N_GRAPHS) return;
        int lo = 0, hi = N_NODES;
        while (lo < hi) { int mid = (lo + hi) >> 1; if (batch[mid] < g) lo = mid + 1; else hi = mid; }
        int s = lo; hi = N_NODES;
        while (lo < hi) { int mid = (lo + hi) >> 1; if (batch[mid] < g + 1) lo = mid + 1; else hi = mid; }
        int c = lo - s;
        inv_cnt[g] = 1.f / (float)(c > 0 ? c : 1);
    }
}

// build per-dst bucket of src ids
__global__ void k_bucket(const int* __restrict__ ei, int* __restrict__ deg,
                         int* __restrict__ bucket) {
    int e = blockIdx.x * 256 + threadIdx.x;
    if (e >= N_EDGES) return;
    int s = ei[e], d = ei[N_EDGES + e];
    int slot = atomicAdd(&deg[d], 1);
    if (slot < CAP) bucket[d * CAP + slot] = s;
}

// Mega GEMM, half-K double pass, 3 blocks/CU:
//   phase 0: layer-1 aggregation fused, 2 threads per (node,head), ~12 live floats
//   per half: phase 1 h2=elu(agg@W1+b1) -> bf16 frag-major As (32 KB);
//             phase 2 MFMA with breg[8] (32 VGPR, survives allocation)
//   epilogue: p2b(bf16) + asad2 via LDS cross-wave reduction
__global__ __launch_bounds__(512, 6) void k_gemm(
    const float* __restrict__ xa, const float* __restrict__ ad4,
    const int* __restrict__ deg, const int* __restrict__ bucket,
    const float* __restrict__ W1, const float* __restrict__ b1,
    const __bf16* __restrict__ wsB,
    const float* __restrict__ a_src2, const float* __restrict__ a_dst2,
    __bf16* __restrict__ p2b, float* __restrict__ asad2) {
    __shared__ __bf16 As[64 * 256];    // 32 KB per half, frag-major: tile t=rt*8+kc, lane*8
    __shared__ __bf16 AgT[64 * 72];    // 9 KB
    __shared__ float red2[64 * 16];    // 4 KB
    const int tid = threadIdx.x;
    const int lane = tid & 63;
    const int w = tid >> 6;
    const int i = lane & 15;
    const int q = lane >> 4;
    const int m0 = blockIdx.x * 64;

    // ---- phase 0: fused layer-1 aggregation, 2 threads per (node,head) ----
    {
        int nh = tid >> 1, sub = tid & 1;
        int r = nh >> 2, h = nh & 3;
        int n = m0 + r;
        float acc[9] = {};
        float z = 0.f;
        bool valid = (n < N_NODES);
        if (valid) {
            float ad = ad4[(size_t)n * 4 + h];
            int dg = deg[n];
            if (dg > CAP) dg = CAP;
            if (sub == 0) {  // self loop
                const f32x4* xp = (const f32x4*)(xa + (size_t)n * 16);
                f32x4 v0 = xp[0], v1 = xp[1], v2 = xp[2], v3 = xp[3];
                float asl = (h == 0) ? v2.y : (h == 1) ? v2.z : (h == 2) ? v2.w : v3.x;
                float e = __expf(lrelu(asl + ad));
                z += e;
                acc[0] += e * v0.x; acc[1] += e * v0.y; acc[2] += e * v0.z; acc[3] += e * v0.w;
                acc[4] += e * v1.x; acc[5] += e * v1.y; acc[6] += e * v1.z; acc[7] += e * v1.w;
                acc[8] += e * v2.x;
            }
            for (int j = sub; j < dg; j += 2) {
                int src = bucket[n * CAP + j];
                const f32x4* xp = (const f32x4*)(xa + (size_t)src * 16);
                f32x4 v0 = xp[0], v1 = xp[1], v2 = xp[2], v3 = xp[3];
                float asl = (h == 0) ? v2.y : (h == 1) ? v2.z : (h == 2) ? v2.w : v3.x;
                float e = __expf(lrelu(asl + ad));
                z += e;
                acc[0] += e * v0.x; acc[1] += e * v0.y; acc[2] += e * v0.z; acc[3] += e * v0.w;
                acc[4] += e * v1.x; acc[5] += e * v1.y; acc[6] += e * v1.z; acc[7] += e * v1.w;
                acc[8] += e * v2.x;
            }
        }
        z += __shfl_xor(z, 1);
#pragma unroll
        for (int k = 0; k < 9; k++) acc[k] += __shfl_xor(acc[k], 1);
        if (sub == 0) {
            float inv = valid ? 1.f / z : 0.f;
            bf16x8 p0;
#pragma unroll
            for (int k = 0; k < 8; k++) p0[k] = (__bf16)(acc[k] * inv);
            __bf16* dst = AgT + r * 72 + h * 16;
            *(bf16x8*)dst = p0;
            dst[8] = (__bf16)(acc[8] * inv);
        }
    }
    __syncthreads();

    f32x4 acc[4];
#pragma unroll
    for (int r = 0; r < 4; r++) acc[r] = (f32x4){0.f, 0.f, 0.f, 0.f};

    const int row = tid & 63;
    const int kg = __builtin_amdgcn_readfirstlane(tid >> 6);  // wave-uniform
    const int rt_p1 = row >> 4, il = row & 15;
    const __bf16* bcol = wsB + (size_t)(w * 16 + i) * 512 + q * 8;

#pragma unroll
    for (int half = 0; half < 2; half++) {
        // B slice for this half (8 x bf16x8 = 32 VGPRs), loads overlap phase 1
        bf16x8 breg[8];
#pragma unroll
        for (int kc = 0; kc < 8; kc++)
            breg[kc] = *(const bf16x8*)(bcol + half * 256 + kc * 32);

        // ---- phase 1: h2 for 256 cols; thread = (row, kg: 32-col group) ----
        {
            int h = half * 2 + (kg >> 2);
            float ag[9];
            {
                bf16x8 a8 = *(const bf16x8*)&AgT[row * 72 + h * 16];
#pragma unroll
                for (int k = 0; k < 8; k++) ag[k] = (float)a8[k];
                ag[8] = (float)AgT[row * 72 + h * 16 + 8];
            }
#pragma unroll
            for (int c8 = 0; c8 < 4; c8++) {
                int j0 = half * 256 + kg * 32 + c8 * 8;
                float o[8];
#pragma unroll
                for (int e = 0; e < 8; e++) o[e] = b1[j0 + e];
#pragma unroll
                for (int k = 0; k < 9; k++) {
                    const float* wp = &W1[k * 512 + j0];
#pragma unroll
                    for (int e = 0; e < 8; e++) o[e] += ag[k] * wp[e];
                }
                bf16x8 pk;
#pragma unroll
                for (int e = 0; e < 8; e++) pk[e] = (__bf16)elu(o[e]);
                *(bf16x8*)&As[(rt_p1 * 8 + kg) * 512 + (c8 * 16 + il) * 8] = pk;
            }
        }
        __syncthreads();

        // ---- phase 2: MFMA sweep over this half's 8 kc-tiles ----
#pragma unroll
        for (int kc = 0; kc < 8; kc++) {
#pragma unroll
            for (int rt = 0; rt < 4; rt++) {
                bf16x8 af = *(const bf16x8*)&As[(rt * 8 + kc) * 512 + lane * 8];
                acc[rt] = __builtin_amdgcn_mfma_f32_16x16x32_bf16(af, breg[kc], acc[rt], 0, 0, 0);
            }
        }
        __syncthreads();   // As reused next half / red2 phase
    }

    // ---- epilogue: p2b + asad2 via LDS cross-wave reduction ----
    float as2 = a_src2[w * 16 + i];
    float ad2 = a_dst2[w * 16 + i];
#pragma unroll
    for (int rt = 0; rt < 4; rt++) {
#pragma unroll
        for (int qq = 0; qq < 4; qq++) {
            int r2 = rt * 16 + q * 4 + qq;
            float v = acc[rt][qq];
            if (m0 + r2 < N_NODES)
                p2b[(size_t)(m0 + r2) * 128 + w * 16 + i] = (__bf16)v;
            float s = v * as2, d = v * ad2;
#pragma unroll
            for (int off = 1; off < 16; off <<= 1) {
                s += __shfl_xor(s, off);
                d += __shfl_xor(d, off);
            }
            if (i == 0) {
                red2[r2 * 16 + w * 2] = s;
                red2[r2 * 16 + w * 2 + 1] = d;
            }
        }
    }
    __syncthreads();
    if (tid < 128) {
        int r2 = tid >> 1, cc = tid & 1;
        float sum = 0.f;
#pragma unroll
        for (int ww = 0; ww < 8; ww++) sum += red2[r2 * 16 + ww * 2 + cc];
        if (m0 + r2 < N_NODES) asad2[(size_t)(m0 + r2) * 2 + cc] = sum;
    }
}

// layer-2 attention + aggregation + elu + fused graph-MEAN (inv_cnt folded in).
__global__ void k_agg2_pool(const __bf16* __restrict__ p2b, const float* __restrict__ asad2,
                            const int* __restrict__ deg, const int* __restrict__ bucket,
                            const float* __restrict__ b2, const int* __restrict__ batch,
                            const float* __restrict__ inv_cnt, float* __restrict__ out) {
    int wv = (blockIdx.x * 256 + threadIdx.x) >> 6;
    wv = __builtin_amdgcn_readfirstlane(wv);
    int lane = threadIdx.x & 63;
    int nbase = wv * 8;
    if (nbase >= N_NODES) return;
    int nend = nbase + 8;
    if (nend > N_NODES) nend = N_NODES;
    float b2a = b2[2 * lane], b2b = b2[2 * lane + 1];
    float g0 = 0.f, g1 = 0.f;
    int curg = batch[nbase];
    for (int n = nbase; n < nend; n++) {
        float ad = asad2[n * 2 + 1];
        float e = __expf(lrelu(asad2[n * 2] + ad));  // self loop
        float z = e;
        bf16x2 v = ((const bf16x2*)(p2b + (size_t)n * 128))[lane];
        float a0 = e * (float)v.x;
        float a1 = e * (float)v.y;
        int dg = deg[n];
        if (dg > CAP) dg = CAP;
        for (int j = 0; j < dg; j++) {
            int s = bucket[n * CAP + j];
            float e2 = __expf(lrelu(asad2[s * 2] + ad));
            z += e2;
            bf16x2 sv = ((const bf16x2*)(p2b + (size_t)s * 128))[lane];
            a0 += e2 * (float)sv.x;
            a1 += e2 * (float)sv.y;
        }
        float inv = 1.f / z;
        float o0 = elu(a0 * inv + b2a);
        float o1 = elu(a1 * inv + b2b);
        int g = batch[n];
        if (g != curg) {
            float ic = inv_cnt[curg];
            atomicAdd(&out[(size_t)curg * 128 + 2 * lane], g0 * ic);
            atomicAdd(&out[(size_t)curg * 128 + 2 * lane + 1], g1 * ic);
            g0 = 0.f; g1 = 0.f; curg = g;
        }
        g0 += o0; g1 += o1;
    }
    float ic = inv_cnt[curg];
    atomicAdd(&out[(size_t)curg * 128 + 2 * lane], g0 * ic);
    atomicAdd(&out[(size_t)curg * 128 + 2 * lane + 1], g1 * ic);
}

extern "C" void kernel_launch(void* const* d_in, const int* in_sizes, int n_in,
                              void* d_out, int out_size, void* d_ws, size_t ws_size,
                              hipStream_t stream) {
    const float* x       = (const float*)d_in[0];
    const int*   ei      = (const int*)d_in[1];
    const int*   batch   = (const int*)d_in[2];
    const float* W1      = (const float*)d_in[3];
    const float* a_src1  = (const float*)d_in[4];
    const float* a_dst1  = (const float*)d_in[5];
    const float* b1      = (const float*)d_in[6];
    const float* W2      = (const float*)d_in[7];
    const float* a_src2  = (const float*)d_in[8];
    const float* a_dst2  = (const float*)d_in[9];
    const float* b2      = (const float*)d_in[10];
    float* out = (float*)d_out;

    float* wsf   = (float*)d_ws;
    float* xa    = wsf + OFF_XA;
    float* ad4   = wsf + OFF_AD4;
    __bf16* p2b  = (__bf16*)(wsf + OFF_P2B);
    float* asad2 = wsf + OFF_ASAD2;
    __bf16* wsB  = (__bf16*)(wsf + OFF_WSB);
    float* invc  = wsf + OFF_INVC;
    int* wsi    = (int*)(wsf + OFF_INT);
    int* deg    = wsi;
    int* bucket = wsi + N_NODES;

    k_pre<<<PRE_INV_END, 256, 0, stream>>>(x, W1, a_src1, a_dst1, W2, batch,
                                           xa, ad4, wsB, deg, out, invc);
    k_bucket<<<(N_EDGES + 255) / 256, 256, 0, stream>>>(ei, deg, bucket);
    k_gemm<<<(N_NODES + 63) / 64, 512, 0, stream>>>(xa, ad4, deg, bucket, W1, b1,
                                                    wsB, a_src2, a_dst2, p2b, asad2);
    k_agg2_pool<<<((N_NODES + 7) / 8 * 64 + 255) / 256, 256, 0, stream>>>(
        p2b, asad2, deg, bucket, b2, batch, invc, out);
}